// Round 4
// baseline (155349.585 us; speedup 1.0000x reference)
//
#include <hip/hip_runtime.h>

// GRU encoder-decoder, round 4.
// 512 blocks x 256 threads (4 waves). Block owns 16 batches (bl = tid&15).
// Group g = tid>>4 (16 groups) owns 4 hidden units j0=4g..4g+3 -> 12 gate
// rows {q*64+4g+c}. Weights: natural row-major, uniform per 16-lane group
// (4 distinct addrs/wave-load), L2-resident. h state: LDS float4 quads
// [kq][bl] -- own state is exactly quad h4[g*16+bl] (b128 rd/wr, contiguous
// per wave). h streamed 16B at a time inside mv (no h[64] array).
// Double-buffered h, 2 barriers/step. 2 blocks/CU (8 waves/CU).
// Register discipline (r2 spilled on h[64] arrays; r3 on the 1024-thread
// VGPR=64 cliff): 256-thread WG + __launch_bounds__(256,2) -> cap 256 VGPR,
// live set ~110 -> no spill.

#define NB 16   // batches per block

__device__ __forceinline__ float sgm(float v) { return 1.f / (1.f + __expf(-v)); }
__device__ __forceinline__ float th(float v)  { float e = __expf(2.f * v); return 1.f - 2.f / (e + 1.f); }

struct P {
  const float *x;
  const float *eWi0, *eWh0, *ebi0, *ebh0, *eWi1, *eWh1, *ebi1, *ebh1;
  const float *dWi0, *dWh0, *dbi0, *dbh0, *dWi1, *dWh1, *dbi1, *dbh1;
  const float *oW, *ob;
  float *out;
};

// acc[q*4+c] += row (q*64+j0+c) of W (192x64 row-major) . h  (h in LDS quads
// [kq*16+bl]). Fully unrolled: 16 kq x (1 ds_read_b128 + 12 dwordx4 + 48 FMA);
// compiler hoists independent loads (VGPR cap 256 gives it room).
__device__ __forceinline__ void mv12(const float* __restrict__ W, int j0,
                                     const float4* __restrict__ h4, int bl,
                                     float acc[12]) {
#pragma unroll
  for (int kq = 0; kq < 16; ++kq) {
    float4 hv = h4[kq * NB + bl];
#pragma unroll
    for (int q = 0; q < 3; ++q) {
#pragma unroll
      for (int c = 0; c < 4; ++c) {
        float4 wv = *(const float4*)(W + (size_t)(q * 64 + j0 + c) * 64 + kq * 4);
        acc[q * 4 + c] += wv.x * hv.x + wv.y * hv.y + wv.z * hv.z + wv.w * hv.w;
      }
    }
  }
}

__global__ __launch_bounds__(256, 2) void gru_main(P p) {
  __shared__ float4 h0A[16 * NB], h0B[16 * NB], h1A[16 * NB], h1B[16 * NB];
  __shared__ float ps[4 * NB];

  const int tid = threadIdx.x;
  const int bl = tid & 15;           // batch lane 0..15
  const int g = tid >> 4;            // group 0..15, owns units 4g..4g+3
  const int w = tid >> 6;            // wave 0..3
  const int b = blockIdx.x * NB + bl;
  const int j0 = 4 * g;

  // zero h state (16*NB = 256 quads = exactly one store per thread)
  h0A[tid] = make_float4(0.f, 0.f, 0.f, 0.f);
  h1A[tid] = make_float4(0.f, 0.f, 0.f, 0.f);
  __syncthreads();

  float4 *h0c = h0A, *h0n = h0B, *h1c = h1A, *h1n = h1B;
  const float ob = p.ob[0];

  // ================= encoder: 512 steps =================
  {
    // per-thread constants: input weight rows (192x2) + biases for 4 units
    float2 wxr[4], wxz[4], wxn[4];
    float bR0[4], bZ0[4], biN0[4], bhN0[4];
    float bR1[4], bZ1[4], biN1[4], bhN1[4];
#pragma unroll
    for (int c = 0; c < 4; ++c) {
      int jr = j0 + c, jz = 64 + j0 + c, jn = 128 + j0 + c;
      wxr[c] = *(const float2*)(p.eWi0 + jr * 2);
      wxz[c] = *(const float2*)(p.eWi0 + jz * 2);
      wxn[c] = *(const float2*)(p.eWi0 + jn * 2);
      bR0[c] = p.ebi0[jr] + p.ebh0[jr];
      bZ0[c] = p.ebi0[jz] + p.ebh0[jz];
      biN0[c] = p.ebi0[jn]; bhN0[c] = p.ebh0[jn];
      bR1[c] = p.ebi1[jr] + p.ebh1[jr];
      bZ1[c] = p.ebi1[jz] + p.ebh1[jz];
      biN1[c] = p.ebi1[jn]; bhN1[c] = p.ebh1[jn];
    }

    float2 xt = *(const float2*)(p.x + (size_t)b * 1024);  // t=0
    for (int t = 0; t < 512; ++t) {
      // prefetch next x (clamped; issued early, used next iter)
      int tn = (t < 511) ? t + 1 : 511;
      float2 xt_nx = *(const float2*)(p.x + (size_t)b * 1024 + tn * 2);

      // ---- cell0: gh = Whh0 @ h0 ----
      float acc[12] = {0,0,0,0,0,0,0,0,0,0,0,0};
      mv12(p.eWh0, j0, h0c, bl, acc);
      float4 o0 = h0c[g * NB + bl];          // own old h0 (4 units)
      float hn[4];
#pragma unroll
      for (int c = 0; c < 4; ++c) {
        float r = sgm(acc[c]     + wxr[c].x * xt.x + wxr[c].y * xt.y + bR0[c]);
        float z = sgm(acc[4 + c] + wxz[c].x * xt.x + wxz[c].y * xt.y + bZ0[c]);
        float n = th(wxn[c].x * xt.x + wxn[c].y * xt.y + biN0[c]
                     + r * (acc[8 + c] + bhN0[c]));
        float ho = (c == 0) ? o0.x : (c == 1) ? o0.y : (c == 2) ? o0.z : o0.w;
        hn[c] = (1.f - z) * n + z * ho;
      }
      h0n[g * NB + bl] = make_float4(hn[0], hn[1], hn[2], hn[3]);
      __syncthreads();

      // ---- cell1: gi = Wih1 @ h0new, gh = Whh1 @ h1 ----
      float ai[12] = {0,0,0,0,0,0,0,0,0,0,0,0};
      mv12(p.eWi1, j0, h0n, bl, ai);
      float ah[12] = {0,0,0,0,0,0,0,0,0,0,0,0};
      mv12(p.eWh1, j0, h1c, bl, ah);
      float4 o1 = h1c[g * NB + bl];
#pragma unroll
      for (int c = 0; c < 4; ++c) {
        float r = sgm(ai[c]     + ah[c]     + bR1[c]);
        float z = sgm(ai[4 + c] + ah[4 + c] + bZ1[c]);
        float n = th(ai[8 + c] + biN1[c] + r * (ah[8 + c] + bhN1[c]));
        float ho = (c == 0) ? o1.x : (c == 1) ? o1.y : (c == 2) ? o1.z : o1.w;
        hn[c] = (1.f - z) * n + z * ho;
      }
      h1n[g * NB + bl] = make_float4(hn[0], hn[1], hn[2], hn[3]);
      __syncthreads();

      xt = xt_nx;
      float4* tmp;
      tmp = h0c; h0c = h0n; h0n = tmp;
      tmp = h1c; h1c = h1n; h1n = tmp;
    }
  }

  // ================= decoder: 180 steps =================
  {
    float wd[12];
    float bR0[4], bZ0[4], biN0[4], bhN0[4];
    float bR1[4], bZ1[4], biN1[4], bhN1[4];
    float oW4[4];
#pragma unroll
    for (int c = 0; c < 4; ++c) {
      int jr = j0 + c, jz = 64 + j0 + c, jn = 128 + j0 + c;
      wd[c] = p.dWi0[jr]; wd[4 + c] = p.dWi0[jz]; wd[8 + c] = p.dWi0[jn];
      bR0[c] = p.dbi0[jr] + p.dbh0[jr];
      bZ0[c] = p.dbi0[jz] + p.dbh0[jz];
      biN0[c] = p.dbi0[jn]; bhN0[c] = p.dbh0[jn];
      bR1[c] = p.dbi1[jr] + p.dbh1[jr];
      bZ1[c] = p.dbi1[jz] + p.dbh1[jz];
      biN1[c] = p.dbi1[jn]; bhN1[c] = p.dbh1[jn];
      oW4[c] = p.oW[j0 + c];
    }

    float prev = 0.f;
    for (int t = 0; t < 180; ++t) {
      // ---- cell0 (input = prev scalar) ----
      float acc[12] = {0,0,0,0,0,0,0,0,0,0,0,0};
      mv12(p.dWh0, j0, h0c, bl, acc);
      float4 o0 = h0c[g * NB + bl];
      float hn[4];
#pragma unroll
      for (int c = 0; c < 4; ++c) {
        float r = sgm(acc[c]     + wd[c] * prev     + bR0[c]);
        float z = sgm(acc[4 + c] + wd[4 + c] * prev + bZ0[c]);
        float n = th(wd[8 + c] * prev + biN0[c] + r * (acc[8 + c] + bhN0[c]));
        float ho = (c == 0) ? o0.x : (c == 1) ? o0.y : (c == 2) ? o0.z : o0.w;
        hn[c] = (1.f - z) * n + z * ho;
      }
      h0n[g * NB + bl] = make_float4(hn[0], hn[1], hn[2], hn[3]);
      __syncthreads();   // barrier A

      // ---- cell1 ----
      float ai[12] = {0,0,0,0,0,0,0,0,0,0,0,0};
      mv12(p.dWi1, j0, h0n, bl, ai);
      float ah[12] = {0,0,0,0,0,0,0,0,0,0,0,0};
      mv12(p.dWh1, j0, h1c, bl, ah);
      float4 o1 = h1c[g * NB + bl];
#pragma unroll
      for (int c = 0; c < 4; ++c) {
        float r = sgm(ai[c]     + ah[c]     + bR1[c]);
        float z = sgm(ai[4 + c] + ah[4 + c] + bZ1[c]);
        float n = th(ai[8 + c] + biN1[c] + r * (ah[8 + c] + bhN1[c]));
        float ho = (c == 0) ? o1.x : (c == 1) ? o1.y : (c == 2) ? o1.z : o1.w;
        hn[c] = (1.f - z) * n + z * ho;
      }
      h1n[g * NB + bl] = make_float4(hn[0], hn[1], hn[2], hn[3]);

      // ---- output: out[b] = sum_j oW[j]*h1new[j][b] + ob ----
      float pv = oW4[0] * hn[0] + oW4[1] * hn[1] + oW4[2] * hn[2] + oW4[3] * hn[3];
      pv += __shfl_xor(pv, 16, 64);          // sum over the wave's 4 groups
      pv += __shfl_xor(pv, 32, 64);
      if ((tid & 48) == 0) ps[w * NB + bl] = pv;   // lane<16 of each wave
      __syncthreads();   // barrier B: ps ready AND h1n drained
      float sum = ob + ps[bl] + ps[NB + bl] + ps[2 * NB + bl] + ps[3 * NB + bl];
      prev = sum;
      if (g == 0) p.out[(size_t)b * 180 + t] = sum;
      // ps rewritten only after next barrier A -> no race with these reads

      float4* tmp;
      tmp = h0c; h0c = h0n; h0n = tmp;
      tmp = h1c; h1c = h1n; h1n = tmp;
    }
  }
}

extern "C" void kernel_launch(void* const* d_in, const int* in_sizes, int n_in,
                              void* d_out, int out_size, void* d_ws, size_t ws_size,
                              hipStream_t stream) {
  P p;
  p.x    = (const float*)d_in[0];
  p.eWi0 = (const float*)d_in[1];
  p.eWh0 = (const float*)d_in[2];
  p.ebi0 = (const float*)d_in[3];
  p.ebh0 = (const float*)d_in[4];
  p.eWi1 = (const float*)d_in[5];
  p.eWh1 = (const float*)d_in[6];
  p.ebi1 = (const float*)d_in[7];
  p.ebh1 = (const float*)d_in[8];
  p.dWi0 = (const float*)d_in[9];
  p.dWh0 = (const float*)d_in[10];
  p.dbi0 = (const float*)d_in[11];
  p.dbh0 = (const float*)d_in[12];
  p.dWi1 = (const float*)d_in[13];
  p.dWh1 = (const float*)d_in[14];
  p.dbi1 = (const float*)d_in[15];
  p.dbh1 = (const float*)d_in[16];
  p.oW   = (const float*)d_in[17];
  p.ob   = (const float*)d_in[18];
  p.out  = (float*)d_out;

  gru_main<<<dim3(512), dim3(256), 0, stream>>>(p);
}

// Round 5
// 24332.092 us; speedup vs baseline: 6.3846x; 6.3846x over previous
//
#include <hip/hip_runtime.h>

// GRU encoder-decoder, round 5 = round-4 structure, spill-pinned.
// 512 blocks x 256 threads (4 waves). Block owns 16 batches (bl = tid&15).
// Group g = tid>>4 (16 groups) owns 4 hidden units j0=4g..4g+3 -> 12 gate
// rows. Weights: natural row-major global, uniform per 16-lane group (4
// distinct 16B addrs per wave-load -> coalesced, L1/L2-resident).
// h state: LDS float4 quads [kq][bl], double-buffered, 2 barriers/step.
// WHY ROUND 2/3/4 DIED: AMDGPU backend targets its own occupancy (4 waves/EU
// -> 128 VGPR) despite launch_bounds, and spills -> 67..284 GB of scratch HBM
// traffic. Fix: amdgpu_waves_per_eu(2,2) pins exactly 2 waves/EU (cap 256
// VGPR, matches the 2048-wave grid), plus unroll-2 (not 16) in the matvec.
// FMA core uses 2-wide float ext-vectors -> v_pk_fma_f32 (2x fp32 rate).

#define NB 16   // batches per block

typedef __attribute__((ext_vector_type(2))) float f32x2;

__device__ __forceinline__ float sgm(float v) { return 1.f / (1.f + __expf(-v)); }
__device__ __forceinline__ float th(float v)  { float e = __expf(2.f * v); return 1.f - 2.f / (e + 1.f); }

struct P {
  const float *x;
  const float *eWi0, *eWh0, *ebi0, *ebh0, *eWi1, *eWh1, *ebi1, *ebh1;
  const float *dWi0, *dWh0, *dbi0, *dbh0, *dWi1, *dWh1, *dbi1, *dbh1;
  const float *oW, *ob;
  float *out;
};

// acc2[q*4+c] += row (q*64+j0+c) of W (192x64 row-major) . h, accumulated as
// f32x2 lanes (even/odd k) -> v_pk_fma_f32. h from LDS quads [kq*NB+bl]
// (2-way bank alias = free). unroll 2: enough pipelining, bounded live set.
__device__ __forceinline__ void mv12(const float* __restrict__ W, int j0,
                                     const float4* __restrict__ h4, int bl,
                                     f32x2 acc[12]) {
#pragma unroll 2
  for (int kq = 0; kq < 16; ++kq) {
    float4 hv = h4[kq * NB + bl];
    f32x2 h01; h01.x = hv.x; h01.y = hv.y;
    f32x2 h23; h23.x = hv.z; h23.y = hv.w;
#pragma unroll
    for (int q = 0; q < 3; ++q) {
#pragma unroll
      for (int c = 0; c < 4; ++c) {
        float4 wv = *(const float4*)(W + (size_t)(q * 64 + j0 + c) * 64 + kq * 4);
        f32x2 w01; w01.x = wv.x; w01.y = wv.y;
        f32x2 w23; w23.x = wv.z; w23.y = wv.w;
        acc[q * 4 + c] = acc[q * 4 + c] + w01 * h01;   // contracts to pk_fma
        acc[q * 4 + c] = acc[q * 4 + c] + w23 * h23;   // contracts to pk_fma
      }
    }
  }
}

__global__ __launch_bounds__(256)
__attribute__((amdgpu_waves_per_eu(2, 2)))
void gru_main(P p) {
  __shared__ float4 h0A[16 * NB], h0B[16 * NB], h1A[16 * NB], h1B[16 * NB];
  __shared__ float ps[4 * NB];

  const int tid = threadIdx.x;
  const int bl = tid & 15;           // batch lane 0..15
  const int g = tid >> 4;            // group 0..15, owns units 4g..4g+3
  const int w = tid >> 6;            // wave 0..3
  const int b = blockIdx.x * NB + bl;
  const int j0 = 4 * g;

  h0A[tid] = make_float4(0.f, 0.f, 0.f, 0.f);
  h1A[tid] = make_float4(0.f, 0.f, 0.f, 0.f);
  __syncthreads();

  float4 *h0c = h0A, *h0n = h0B, *h1c = h1A, *h1n = h1B;
  const float ob = p.ob[0];

  // ================= encoder: 512 steps =================
  {
    float2 wxr[4], wxz[4], wxn[4];
    float bR0[4], bZ0[4], biN0[4], bhN0[4];
    float bR1[4], bZ1[4], biN1[4], bhN1[4];
#pragma unroll
    for (int c = 0; c < 4; ++c) {
      int jr = j0 + c, jz = 64 + j0 + c, jn = 128 + j0 + c;
      wxr[c] = *(const float2*)(p.eWi0 + jr * 2);
      wxz[c] = *(const float2*)(p.eWi0 + jz * 2);
      wxn[c] = *(const float2*)(p.eWi0 + jn * 2);
      bR0[c] = p.ebi0[jr] + p.ebh0[jr];
      bZ0[c] = p.ebi0[jz] + p.ebh0[jz];
      biN0[c] = p.ebi0[jn]; bhN0[c] = p.ebh0[jn];
      bR1[c] = p.ebi1[jr] + p.ebh1[jr];
      bZ1[c] = p.ebi1[jz] + p.ebh1[jz];
      biN1[c] = p.ebi1[jn]; bhN1[c] = p.ebh1[jn];
    }

    float2 xt = *(const float2*)(p.x + (size_t)b * 1024);  // t=0
    for (int t = 0; t < 512; ++t) {
      int tn = (t < 511) ? t + 1 : 511;
      float2 xt_nx = *(const float2*)(p.x + (size_t)b * 1024 + tn * 2);

      // ---- cell0: gh = Whh0 @ h0 ----
      f32x2 acc[12];
#pragma unroll
      for (int i = 0; i < 12; ++i) { acc[i].x = 0.f; acc[i].y = 0.f; }
      mv12(p.eWh0, j0, h0c, bl, acc);
      float4 o0 = h0c[g * NB + bl];
      float hn[4];
#pragma unroll
      for (int c = 0; c < 4; ++c) {
        float ar = acc[c].x + acc[c].y;
        float az = acc[4 + c].x + acc[4 + c].y;
        float an = acc[8 + c].x + acc[8 + c].y;
        float r = sgm(ar + wxr[c].x * xt.x + wxr[c].y * xt.y + bR0[c]);
        float z = sgm(az + wxz[c].x * xt.x + wxz[c].y * xt.y + bZ0[c]);
        float n = th(wxn[c].x * xt.x + wxn[c].y * xt.y + biN0[c]
                     + r * (an + bhN0[c]));
        float ho = (c == 0) ? o0.x : (c == 1) ? o0.y : (c == 2) ? o0.z : o0.w;
        hn[c] = (1.f - z) * n + z * ho;
      }
      h0n[g * NB + bl] = make_float4(hn[0], hn[1], hn[2], hn[3]);
      __syncthreads();

      // ---- cell1: gi = Wih1 @ h0new, gh = Whh1 @ h1 ----
      f32x2 ai[12], ah[12];
#pragma unroll
      for (int i = 0; i < 12; ++i) {
        ai[i].x = 0.f; ai[i].y = 0.f;
        ah[i].x = 0.f; ah[i].y = 0.f;
      }
      mv12(p.eWi1, j0, h0n, bl, ai);
      mv12(p.eWh1, j0, h1c, bl, ah);
      float4 o1 = h1c[g * NB + bl];
#pragma unroll
      for (int c = 0; c < 4; ++c) {
        float air = ai[c].x + ai[c].y,     ahr = ah[c].x + ah[c].y;
        float aiz = ai[4 + c].x + ai[4 + c].y, ahz = ah[4 + c].x + ah[4 + c].y;
        float ain = ai[8 + c].x + ai[8 + c].y, ahn = ah[8 + c].x + ah[8 + c].y;
        float r = sgm(air + ahr + bR1[c]);
        float z = sgm(aiz + ahz + bZ1[c]);
        float n = th(ain + biN1[c] + r * (ahn + bhN1[c]));
        float ho = (c == 0) ? o1.x : (c == 1) ? o1.y : (c == 2) ? o1.z : o1.w;
        hn[c] = (1.f - z) * n + z * ho;
      }
      h1n[g * NB + bl] = make_float4(hn[0], hn[1], hn[2], hn[3]);
      __syncthreads();

      xt = xt_nx;
      float4* tmp;
      tmp = h0c; h0c = h0n; h0n = tmp;
      tmp = h1c; h1c = h1n; h1n = tmp;
    }
  }

  // ================= decoder: 180 steps =================
  {
    float wd[12];
    float bR0[4], bZ0[4], biN0[4], bhN0[4];
    float bR1[4], bZ1[4], biN1[4], bhN1[4];
    float oW4[4];
#pragma unroll
    for (int c = 0; c < 4; ++c) {
      int jr = j0 + c, jz = 64 + j0 + c, jn = 128 + j0 + c;
      wd[c] = p.dWi0[jr]; wd[4 + c] = p.dWi0[jz]; wd[8 + c] = p.dWi0[jn];
      bR0[c] = p.dbi0[jr] + p.dbh0[jr];
      bZ0[c] = p.dbi0[jz] + p.dbh0[jz];
      biN0[c] = p.dbi0[jn]; bhN0[c] = p.dbh0[jn];
      bR1[c] = p.dbi1[jr] + p.dbh1[jr];
      bZ1[c] = p.dbi1[jz] + p.dbh1[jz];
      biN1[c] = p.dbi1[jn]; bhN1[c] = p.dbh1[jn];
      oW4[c] = p.oW[j0 + c];
    }

    float prev = 0.f;
    for (int t = 0; t < 180; ++t) {
      // ---- cell0 (input = prev scalar) ----
      f32x2 acc[12];
#pragma unroll
      for (int i = 0; i < 12; ++i) { acc[i].x = 0.f; acc[i].y = 0.f; }
      mv12(p.dWh0, j0, h0c, bl, acc);
      float4 o0 = h0c[g * NB + bl];
      float hn[4];
#pragma unroll
      for (int c = 0; c < 4; ++c) {
        float ar = acc[c].x + acc[c].y;
        float az = acc[4 + c].x + acc[4 + c].y;
        float an = acc[8 + c].x + acc[8 + c].y;
        float r = sgm(ar + wd[c] * prev + bR0[c]);
        float z = sgm(az + wd[4 + c] * prev + bZ0[c]);
        float n = th(wd[8 + c] * prev + biN0[c] + r * (an + bhN0[c]));
        float ho = (c == 0) ? o0.x : (c == 1) ? o0.y : (c == 2) ? o0.z : o0.w;
        hn[c] = (1.f - z) * n + z * ho;
      }
      h0n[g * NB + bl] = make_float4(hn[0], hn[1], hn[2], hn[3]);
      __syncthreads();   // barrier A

      // ---- cell1 ----
      f32x2 ai[12], ah[12];
#pragma unroll
      for (int i = 0; i < 12; ++i) {
        ai[i].x = 0.f; ai[i].y = 0.f;
        ah[i].x = 0.f; ah[i].y = 0.f;
      }
      mv12(p.dWi1, j0, h0n, bl, ai);
      mv12(p.dWh1, j0, h1c, bl, ah);
      float4 o1 = h1c[g * NB + bl];
#pragma unroll
      for (int c = 0; c < 4; ++c) {
        float air = ai[c].x + ai[c].y,         ahr = ah[c].x + ah[c].y;
        float aiz = ai[4 + c].x + ai[4 + c].y, ahz = ah[4 + c].x + ah[4 + c].y;
        float ain = ai[8 + c].x + ai[8 + c].y, ahn = ah[8 + c].x + ah[8 + c].y;
        float r = sgm(air + ahr + bR1[c]);
        float z = sgm(aiz + ahz + bZ1[c]);
        float n = th(ain + biN1[c] + r * (ahn + bhN1[c]));
        float ho = (c == 0) ? o1.x : (c == 1) ? o1.y : (c == 2) ? o1.z : o1.w;
        hn[c] = (1.f - z) * n + z * ho;
      }
      h1n[g * NB + bl] = make_float4(hn[0], hn[1], hn[2], hn[3]);

      // ---- output: out[b] = sum_j oW[j]*h1new[j][b] + ob ----
      float pv = oW4[0] * hn[0] + oW4[1] * hn[1] + oW4[2] * hn[2] + oW4[3] * hn[3];
      pv += __shfl_xor(pv, 16, 64);
      pv += __shfl_xor(pv, 32, 64);
      if ((tid & 48) == 0) ps[w * NB + bl] = pv;
      __syncthreads();   // barrier B: ps ready AND h1n drained
      float sum = ob + ps[bl] + ps[NB + bl] + ps[2 * NB + bl] + ps[3 * NB + bl];
      prev = sum;
      if (g == 0) p.out[(size_t)b * 180 + t] = sum;

      float4* tmp;
      tmp = h0c; h0c = h0n; h0n = tmp;
      tmp = h1c; h1c = h1n; h1n = tmp;
    }
  }
}

extern "C" void kernel_launch(void* const* d_in, const int* in_sizes, int n_in,
                              void* d_out, int out_size, void* d_ws, size_t ws_size,
                              hipStream_t stream) {
  P p;
  p.x    = (const float*)d_in[0];
  p.eWi0 = (const float*)d_in[1];
  p.eWh0 = (const float*)d_in[2];
  p.ebi0 = (const float*)d_in[3];
  p.ebh0 = (const float*)d_in[4];
  p.eWi1 = (const float*)d_in[5];
  p.eWh1 = (const float*)d_in[6];
  p.ebi1 = (const float*)d_in[7];
  p.ebh1 = (const float*)d_in[8];
  p.dWi0 = (const float*)d_in[9];
  p.dWh0 = (const float*)d_in[10];
  p.dbi0 = (const float*)d_in[11];
  p.dbh0 = (const float*)d_in[12];
  p.dWi1 = (const float*)d_in[13];
  p.dWh1 = (const float*)d_in[14];
  p.dbi1 = (const float*)d_in[15];
  p.dbh1 = (const float*)d_in[16];
  p.oW   = (const float*)d_in[17];
  p.ob   = (const float*)d_in[18];
  p.out  = (float*)d_out;

  gru_main<<<dim3(512), dim3(256), 0, stream>>>(p);
}

// Round 6
// 12888.538 us; speedup vs baseline: 12.0533x; 1.8879x over previous
//
#include <hip/hip_runtime.h>

// GRU encoder-decoder, round 6: 2-units x 2-batches per thread.
// 512 blocks x 256 threads (4 waves; ~2 blocks/CU). Block owns 16 batches.
// bg = tid&7 owns batches {2bg,2bg+1}; rg = tid>>3 (0..31) owns hidden units
// {2rg,2rg+1} -> 6 gate rows {q*64+2rg+c}. FMAs are v_pk_fma over the batch
// pair (f32x2), so weight loads amortize 2x and rows amortize h reads.
// Weights: natural row-major global, 6 base ptrs + immediate offsets,
// 8 distinct 16B addrs per wave-instr, L1/L2-resident.
// h state: LDS float4 [kpair][bg] = (h[2kp][b0],h[2kp][b1],h[2kp+1][b0],
// h[2kp+1][b1]); the gating thread's output IS quad kp=rg -> one b128
// write/read, conflict-free, double-buffered, 2 barriers/step.
// amdgpu_waves_per_eu(2,2) pin (r5-proven) prevents the backend's
// occupancy-driven spill (r2/r3/r4: 67..284 GB scratch traffic).

#define NBB 16   // batches per block
#define NBG 8    // batch groups of 2

typedef __attribute__((ext_vector_type(2))) float f32x2;

__device__ __forceinline__ f32x2 sgm2(f32x2 v) {
  f32x2 r;
  r.x = 1.f / (1.f + __expf(-v.x));
  r.y = 1.f / (1.f + __expf(-v.y));
  return r;
}
__device__ __forceinline__ f32x2 th2(f32x2 v) {
  f32x2 r;
  float e0 = __expf(2.f * v.x), e1 = __expf(2.f * v.y);
  r.x = 1.f - 2.f / (e0 + 1.f);
  r.y = 1.f - 2.f / (e1 + 1.f);
  return r;
}

struct P {
  const float *x;
  const float *eWi0, *eWh0, *ebi0, *ebh0, *eWi1, *eWh1, *ebi1, *ebh1;
  const float *dWi0, *dWh0, *dbi0, *dbh0, *dWi1, *dWh1, *dbi1, *dbh1;
  const float *oW, *ob;
  float *out;
};

// acc[q*2+c] (f32x2 over batch pair) += row(q*64+u0+c) of W (192x64) . h
// h in LDS quads [kp][bg]; weights via 6 base ptrs + imm offsets.
__device__ __forceinline__ void mv6(const float* __restrict__ W, int u0,
                                    const float4* __restrict__ hq, int bg,
                                    f32x2 acc[6]) {
  const float4* wp0 = (const float4*)(W + (size_t)u0 * 64);
  const float4* wp1 = (const float4*)(W + (size_t)(u0 + 1) * 64);
  const float4* wp2 = (const float4*)(W + (size_t)(64 + u0) * 64);
  const float4* wp3 = (const float4*)(W + (size_t)(64 + u0 + 1) * 64);
  const float4* wp4 = (const float4*)(W + (size_t)(128 + u0) * 64);
  const float4* wp5 = (const float4*)(W + (size_t)(128 + u0 + 1) * 64);
#pragma unroll 4
  for (int kq = 0; kq < 16; ++kq) {
    float4 ha = hq[(2 * kq) * NBG + bg];       // k=4kq,4kq+1
    float4 hb = hq[(2 * kq + 1) * NBG + bg];   // k=4kq+2,4kq+3
    f32x2 h0; h0.x = ha.x; h0.y = ha.y;
    f32x2 h1; h1.x = ha.z; h1.y = ha.w;
    f32x2 h2; h2.x = hb.x; h2.y = hb.y;
    f32x2 h3; h3.x = hb.z; h3.y = hb.w;
    float4 w;
    w = wp0[kq];
    acc[0] += h0 * w.x; acc[0] += h1 * w.y; acc[0] += h2 * w.z; acc[0] += h3 * w.w;
    w = wp1[kq];
    acc[1] += h0 * w.x; acc[1] += h1 * w.y; acc[1] += h2 * w.z; acc[1] += h3 * w.w;
    w = wp2[kq];
    acc[2] += h0 * w.x; acc[2] += h1 * w.y; acc[2] += h2 * w.z; acc[2] += h3 * w.w;
    w = wp3[kq];
    acc[3] += h0 * w.x; acc[3] += h1 * w.y; acc[3] += h2 * w.z; acc[3] += h3 * w.w;
    w = wp4[kq];
    acc[4] += h0 * w.x; acc[4] += h1 * w.y; acc[4] += h2 * w.z; acc[4] += h3 * w.w;
    w = wp5[kq];
    acc[5] += h0 * w.x; acc[5] += h1 * w.y; acc[5] += h2 * w.z; acc[5] += h3 * w.w;
  }
}

__global__ __launch_bounds__(256)
__attribute__((amdgpu_waves_per_eu(2, 2)))
void gru_main(P p) {
  __shared__ float4 h0A[32 * NBG], h0B[32 * NBG], h1A[32 * NBG], h1B[32 * NBG];
  __shared__ f32x2 ps[4 * NBG];

  const int tid = threadIdx.x;
  const int bg = tid & 7;            // batch group: batches 2bg, 2bg+1
  const int rg = tid >> 3;           // row group 0..31: units 2rg, 2rg+1
  const int wv = tid >> 6;           // wave 0..3
  const int u0 = 2 * rg;
  const int bb = blockIdx.x * NBB + 2 * bg;   // first batch of the pair

  h0A[tid] = make_float4(0.f, 0.f, 0.f, 0.f);   // 32*NBG == 256 == blockDim
  h1A[tid] = make_float4(0.f, 0.f, 0.f, 0.f);
  __syncthreads();

  float4 *h0c = h0A, *h0n = h0B, *h1c = h1A, *h1n = h1B;
  const float ob = p.ob[0];

  // ================= encoder: 512 steps =================
  {
    float2 wxr[2], wxz[2], wxn[2];
    float bR0[2], bZ0[2], biN0[2], bhN0[2];
    float bR1[2], bZ1[2], biN1[2], bhN1[2];
#pragma unroll
    for (int c = 0; c < 2; ++c) {
      int jr = u0 + c, jz = 64 + u0 + c, jn = 128 + u0 + c;
      wxr[c] = *(const float2*)(p.eWi0 + jr * 2);
      wxz[c] = *(const float2*)(p.eWi0 + jz * 2);
      wxn[c] = *(const float2*)(p.eWi0 + jn * 2);
      bR0[c] = p.ebi0[jr] + p.ebh0[jr];
      bZ0[c] = p.ebi0[jz] + p.ebh0[jz];
      biN0[c] = p.ebi0[jn]; bhN0[c] = p.ebh0[jn];
      bR1[c] = p.ebi1[jr] + p.ebh1[jr];
      bZ1[c] = p.ebi1[jz] + p.ebh1[jz];
      biN1[c] = p.ebi1[jn]; bhN1[c] = p.ebh1[jn];
    }

    float2 xa = *(const float2*)(p.x + (size_t)bb * 1024);
    float2 xb = *(const float2*)(p.x + (size_t)(bb + 1) * 1024);
    for (int t = 0; t < 512; ++t) {
      int tn = (t < 511) ? t + 1 : 511;     // prefetch next x
      float2 xa_nx = *(const float2*)(p.x + (size_t)bb * 1024 + tn * 2);
      float2 xb_nx = *(const float2*)(p.x + (size_t)(bb + 1) * 1024 + tn * 2);
      f32x2 X0; X0.x = xa.x; X0.y = xb.x;   // feature 0, batch pair
      f32x2 X1; X1.x = xa.y; X1.y = xb.y;   // feature 1

      // ---- cell0: gh = Whh0 @ h0 ----
      f32x2 acc[6];
#pragma unroll
      for (int i = 0; i < 6; ++i) { acc[i].x = 0.f; acc[i].y = 0.f; }
      mv6(p.eWh0, u0, h0c, bg, acc);
      float4 o = h0c[rg * NBG + bg];
      f32x2 old0; old0.x = o.x; old0.y = o.y;
      f32x2 old1; old1.x = o.z; old1.y = o.w;
      f32x2 hn0, hn1;
      {
        f32x2 r = sgm2(acc[0] + (wxr[0].x * X0 + wxr[0].y * X1) + bR0[0]);
        f32x2 z = sgm2(acc[2] + (wxz[0].x * X0 + wxz[0].y * X1) + bZ0[0]);
        f32x2 n = th2((wxn[0].x * X0 + wxn[0].y * X1) + biN0[0]
                      + r * (acc[4] + bhN0[0]));
        hn0 = (1.f - z) * n + z * old0;
        r = sgm2(acc[1] + (wxr[1].x * X0 + wxr[1].y * X1) + bR0[1]);
        z = sgm2(acc[3] + (wxz[1].x * X0 + wxz[1].y * X1) + bZ0[1]);
        n = th2((wxn[1].x * X0 + wxn[1].y * X1) + biN0[1]
                + r * (acc[5] + bhN0[1]));
        hn1 = (1.f - z) * n + z * old1;
      }
      h0n[rg * NBG + bg] = make_float4(hn0.x, hn0.y, hn1.x, hn1.y);
      __syncthreads();

      // ---- cell1: gi = Wih1 @ h0new, gh = Whh1 @ h1 ----
      f32x2 ai[6], ah[6];
#pragma unroll
      for (int i = 0; i < 6; ++i) {
        ai[i].x = 0.f; ai[i].y = 0.f;
        ah[i].x = 0.f; ah[i].y = 0.f;
      }
      mv6(p.eWi1, u0, h0n, bg, ai);
      mv6(p.eWh1, u0, h1c, bg, ah);
      o = h1c[rg * NBG + bg];
      old0.x = o.x; old0.y = o.y;
      old1.x = o.z; old1.y = o.w;
      {
        f32x2 r = sgm2(ai[0] + ah[0] + bR1[0]);
        f32x2 z = sgm2(ai[2] + ah[2] + bZ1[0]);
        f32x2 n = th2(ai[4] + biN1[0] + r * (ah[4] + bhN1[0]));
        hn0 = (1.f - z) * n + z * old0;
        r = sgm2(ai[1] + ah[1] + bR1[1]);
        z = sgm2(ai[3] + ah[3] + bZ1[1]);
        n = th2(ai[5] + biN1[1] + r * (ah[5] + bhN1[1]));
        hn1 = (1.f - z) * n + z * old1;
      }
      h1n[rg * NBG + bg] = make_float4(hn0.x, hn0.y, hn1.x, hn1.y);
      __syncthreads();

      xa = xa_nx; xb = xb_nx;
      float4* tmp;
      tmp = h0c; h0c = h0n; h0n = tmp;
      tmp = h1c; h1c = h1n; h1n = tmp;
    }
  }

  // ================= decoder: 180 steps =================
  {
    float wdR[2], wdZ[2], wdN[2];
    float bR0[2], bZ0[2], biN0[2], bhN0[2];
    float bR1[2], bZ1[2], biN1[2], bhN1[2];
    float oW0, oW1;
#pragma unroll
    for (int c = 0; c < 2; ++c) {
      int jr = u0 + c, jz = 64 + u0 + c, jn = 128 + u0 + c;
      wdR[c] = p.dWi0[jr]; wdZ[c] = p.dWi0[jz]; wdN[c] = p.dWi0[jn];
      bR0[c] = p.dbi0[jr] + p.dbh0[jr];
      bZ0[c] = p.dbi0[jz] + p.dbh0[jz];
      biN0[c] = p.dbi0[jn]; bhN0[c] = p.dbh0[jn];
      bR1[c] = p.dbi1[jr] + p.dbh1[jr];
      bZ1[c] = p.dbi1[jz] + p.dbh1[jz];
      biN1[c] = p.dbi1[jn]; bhN1[c] = p.dbh1[jn];
    }
    oW0 = p.oW[u0]; oW1 = p.oW[u0 + 1];

    f32x2 prev; prev.x = 0.f; prev.y = 0.f;
    for (int t = 0; t < 180; ++t) {
      // ---- cell0 (input = prev, scalar per batch) ----
      f32x2 acc[6];
#pragma unroll
      for (int i = 0; i < 6; ++i) { acc[i].x = 0.f; acc[i].y = 0.f; }
      mv6(p.dWh0, u0, h0c, bg, acc);
      float4 o = h0c[rg * NBG + bg];
      f32x2 old0; old0.x = o.x; old0.y = o.y;
      f32x2 old1; old1.x = o.z; old1.y = o.w;
      f32x2 hn0, hn1;
      {
        f32x2 r = sgm2(acc[0] + wdR[0] * prev + bR0[0]);
        f32x2 z = sgm2(acc[2] + wdZ[0] * prev + bZ0[0]);
        f32x2 n = th2(wdN[0] * prev + biN0[0] + r * (acc[4] + bhN0[0]));
        hn0 = (1.f - z) * n + z * old0;
        r = sgm2(acc[1] + wdR[1] * prev + bR0[1]);
        z = sgm2(acc[3] + wdZ[1] * prev + bZ0[1]);
        n = th2(wdN[1] * prev + biN0[1] + r * (acc[5] + bhN0[1]));
        hn1 = (1.f - z) * n + z * old1;
      }
      h0n[rg * NBG + bg] = make_float4(hn0.x, hn0.y, hn1.x, hn1.y);
      __syncthreads();   // barrier A

      // ---- cell1 ----
      f32x2 ai[6], ah[6];
#pragma unroll
      for (int i = 0; i < 6; ++i) {
        ai[i].x = 0.f; ai[i].y = 0.f;
        ah[i].x = 0.f; ah[i].y = 0.f;
      }
      mv6(p.dWi1, u0, h0n, bg, ai);
      mv6(p.dWh1, u0, h1c, bg, ah);
      o = h1c[rg * NBG + bg];
      old0.x = o.x; old0.y = o.y;
      old1.x = o.z; old1.y = o.w;
      {
        f32x2 r = sgm2(ai[0] + ah[0] + bR1[0]);
        f32x2 z = sgm2(ai[2] + ah[2] + bZ1[0]);
        f32x2 n = th2(ai[4] + biN1[0] + r * (ah[4] + bhN1[0]));
        hn0 = (1.f - z) * n + z * old0;
        r = sgm2(ai[1] + ah[1] + bR1[1]);
        z = sgm2(ai[3] + ah[3] + bZ1[1]);
        n = th2(ai[5] + biN1[1] + r * (ah[5] + bhN1[1]));
        hn1 = (1.f - z) * n + z * old1;
      }
      h1n[rg * NBG + bg] = make_float4(hn0.x, hn0.y, hn1.x, hn1.y);

      // ---- output: out[b] = sum_j oW[j]*h1new[j][b] + ob ----
      f32x2 pv = hn0 * oW0 + hn1 * oW1;
      pv.x += __shfl_xor(pv.x, 8, 64);
      pv.y += __shfl_xor(pv.y, 8, 64);
      pv.x += __shfl_xor(pv.x, 16, 64);
      pv.y += __shfl_xor(pv.y, 16, 64);
      pv.x += __shfl_xor(pv.x, 32, 64);
      pv.y += __shfl_xor(pv.y, 32, 64);
      if ((tid & 0x38) == 0) ps[wv * NBG + bg] = pv;   // lanes 0..7 per wave
      __syncthreads();   // barrier B: ps ready AND h1n drained
      f32x2 sum = ps[bg] + ps[NBG + bg] + ps[2 * NBG + bg] + ps[3 * NBG + bg];
      sum += ob;
      prev = sum;
      if (rg == 0) {
        p.out[(size_t)bb * 180 + t] = sum.x;
        p.out[(size_t)(bb + 1) * 180 + t] = sum.y;
      }
      // ps is rewritten only after the next barrier A -> no race.

      float4* tmp;
      tmp = h0c; h0c = h0n; h0n = tmp;
      tmp = h1c; h1c = h1n; h1n = tmp;
    }
  }
}

extern "C" void kernel_launch(void* const* d_in, const int* in_sizes, int n_in,
                              void* d_out, int out_size, void* d_ws, size_t ws_size,
                              hipStream_t stream) {
  P p;
  p.x    = (const float*)d_in[0];
  p.eWi0 = (const float*)d_in[1];
  p.eWh0 = (const float*)d_in[2];
  p.ebi0 = (const float*)d_in[3];
  p.ebh0 = (const float*)d_in[4];
  p.eWi1 = (const float*)d_in[5];
  p.eWh1 = (const float*)d_in[6];
  p.ebi1 = (const float*)d_in[7];
  p.ebh1 = (const float*)d_in[8];
  p.dWi0 = (const float*)d_in[9];
  p.dWh0 = (const float*)d_in[10];
  p.dbi0 = (const float*)d_in[11];
  p.dbh0 = (const float*)d_in[12];
  p.dWi1 = (const float*)d_in[13];
  p.dWh1 = (const float*)d_in[14];
  p.dbi1 = (const float*)d_in[15];
  p.dbh1 = (const float*)d_in[16];
  p.oW   = (const float*)d_in[17];
  p.ob   = (const float*)d_in[18];
  p.out  = (float*)d_out;

  gru_main<<<dim3(512), dim3(256), 0, stream>>>(p);
}